// Round 10
// baseline (352.103 us; speedup 1.0000x reference)
//
#include <hip/hip_runtime.h>
#include <hip/hip_bf16.h>

typedef __attribute__((ext_vector_type(8))) short short8;
typedef __attribute__((ext_vector_type(4))) float f32x4;
typedef __attribute__((ext_vector_type(16))) float f32x16;
typedef __attribute__((ext_vector_type(4))) unsigned int u32x4;

#define NB 8
#define NC 256
#define NNN 4096
#define L2E 1.44269504088896f

__device__ __forceinline__ ushort f2bf(float f) {
  __hip_bfloat16 h = __float2bfloat16(f);
  return *reinterpret_cast<ushort*>(&h);
}
// truncation-pack: low16 = bf16_trunc(a), high16 = bf16_trunc(b)
__device__ __forceinline__ unsigned pack2t(float a, float b) {
  const unsigned ua = __builtin_bit_cast(unsigned, a);
  const unsigned ub = __builtin_bit_cast(unsigned, b);
  return (ua >> 16) | (ub & 0xFFFF0000u);
}
__device__ __forceinline__ void gload16(const void* g, void* l) {
  __builtin_amdgcn_global_load_lds(
      (const __attribute__((address_space(1))) void*)g,
      (__attribute__((address_space(3))) void*)l, 16, 0, 0);
}

// fTs[b][n][c ^ ((n&7)<<3)] = bf16(x[b][c][n])   (chunk-swizzled rows, 512B)
__global__ __launch_bounds__(256) void prep_T(const float* __restrict__ x,
                                              ushort* __restrict__ fTs) {
  __shared__ float tile[32][33];
  const int tx = threadIdx.x, ty = threadIdx.y;
  const int n0 = blockIdx.x * 32, c0 = blockIdx.y * 32, b = blockIdx.z;
#pragma unroll
  for (int k = 0; k < 4; ++k) {
    tile[ty + 8 * k][tx] =
        x[((size_t)(b * NC + c0 + ty + 8 * k)) * NNN + n0 + tx];
  }
  __syncthreads();
#pragma unroll
  for (int k = 0; k < 4; ++k) {
    const int n = n0 + ty + 8 * k;
    const int c = c0 + tx;
    fTs[(size_t)(b * NNN + n) * NC + (c ^ ((n & 7) << 3))] =
        f2bf(tile[tx][ty + 8 * k]);
  }
}

// fVs: per batch, per 64-m tile: [8 m-chunks][256 c][8 ushorts]
// value(b,c,m) at b*NNN*NC + (m>>6)*16384 + ((m&63)>>3)*2048 + c*8 + (m&7)
__global__ __launch_bounds__(256) void prep_V(const float* __restrict__ x,
                                              ushort* __restrict__ fVs) {
  __shared__ float vt[32][65];
  const int tx = threadIdx.x & 63;  // m within tile
  const int ty = threadIdx.x >> 6;  // 0..3
  const int t = blockIdx.x;         // m-tile
  const int cb = blockIdx.y;        // c-block of 32
  const int b = blockIdx.z;
  const float* xb = x + (size_t)b * NC * NNN;
#pragma unroll
  for (int j = 0; j < 8; ++j) {
    const int cl = ty + 4 * j;  // 0..31
    vt[cl][tx] = xb[(size_t)(cb * 32 + cl) * NNN + t * 64 + tx];
  }
  __syncthreads();
  const int c = threadIdx.x & 31;
  const int mc = threadIdx.x >> 5;  // 0..7
  short8 w;
#pragma unroll
  for (int e = 0; e < 8; ++e) w[e] = (short)f2bf(vt[c][mc * 8 + e]);
  *(short8*)(fVs + (size_t)b * NNN * NC + (size_t)t * 16384 + mc * 2048 +
             (cb * 32 + c) * 8) = w;
}

// Flash attention, 32x32x16 bf16 MFMA, swapped QK^T, in-register softmax.
// R4 structure: 4 waves x 32 query cols, 64-m tiles, dbuf 2x64KB, one
// __syncthreads per tile. V-path = conflict-free chunk layout; K-path = R4.
__global__ __launch_bounds__(256, 1) void attn_kernel(
    const float* __restrict__ x, const ushort* __restrict__ fTs,
    const ushort* __restrict__ fVs, const float* __restrict__ gamma,
    float* __restrict__ out) {
  __shared__ __align__(16) char smem[131072];

  const int tid = threadIdx.x;
  const int w = tid >> 6;
  const int l = tid & 63;
  const int l31 = l & 31;
  const int h = l >> 5;
  const int b = blockIdx.x & 7;             // batch -> XCD
  const int n0w = (blockIdx.x >> 3) * 128 + w * 32;

  const char* fTb = (const char*)(fTs + (size_t)b * NNN * NC);
  const char* fVb = (const char*)(fVs + (size_t)b * NNN * NC);

  // Q fragments (B operand): col n = l31 -> row n0w+l31; k = kc*16+8h+j
  short8 q[16];
  {
    const int n = n0w + l31;
    const char* qrow = fTb + (size_t)n * 512;
    const int sw = (n & 7) << 4;
#pragma unroll
    for (int kc = 0; kc < 16; ++kc)
      q[kc] = *(const short8*)(qrow + ((kc * 32 + 16 * h) ^ sw));
  }

  f32x16 o[8];
#pragma unroll
  for (int cf = 0; cf < 8; ++cf)
#pragma unroll
    for (int r = 0; r < 16; ++r) o[cf][r] = 0.f;
  float m_run = -3.0e38f, l_run = 0.f;

  // staging sources (per-lane), dest linear per wave
  const int krow = w * 16 + (l >> 5);
  const char* gK0 = fTb + (size_t)krow * 512 + (l & 31) * 16;
  const char* gV0 = fVb + tid * 16;

  // prologue: stage tile 0 into buffer 0 (K @0, V @32768)
#pragma unroll
  for (int i = 0; i < 8; ++i)
    gload16(gK0 + (size_t)i * 1024, smem + w * 8192 + i * 1024);
#pragma unroll
  for (int j = 0; j < 8; ++j)
    gload16(gV0 + (size_t)j * 4096, smem + 32768 + w * 1024 + j * 4096);
  __syncthreads();

  for (int t = 0; t < 64; ++t) {
    const int p = t & 1;
    char* bufC = smem + p * 65536;
    char* bufN = smem + (p ^ 1) * 65536;
    // issue next tile's staging; completes during this tile's compute
    if (t < 63) {
      const size_t kOff = (size_t)(t + 1) * 32768;
      const size_t vOff = (size_t)(t + 1) * 32768;
#pragma unroll
      for (int i = 0; i < 8; ++i)
        gload16(gK0 + kOff + (size_t)i * 1024, bufN + w * 8192 + i * 1024);
#pragma unroll
      for (int j = 0; j < 8; ++j)
        gload16(gV0 + vOff + (size_t)j * 4096,
                bufN + 32768 + w * 1024 + j * 4096);
    }

    // ---- S^T = K * Q^T : A = K rows m (LDS), B = Q cols n (regs) ----
    const char* Kp = bufC;
    f32x16 s0, s1;
#pragma unroll
    for (int r = 0; r < 16; ++r) { s0[r] = 0.f; s1[r] = 0.f; }
#pragma unroll
    for (int kc = 0; kc < 16; ++kc) {
      const int bb = (kc * 32 + 16 * h) ^ ((l31 & 7) << 4);
      short8 ka0 = *(const short8*)(Kp + l31 * 512 + bb);
      short8 ka1 = *(const short8*)(Kp + (32 + l31) * 512 + bb);
      s0 = __builtin_amdgcn_mfma_f32_32x32x16_bf16(ka0, q[kc], s0, 0, 0, 0);
      s1 = __builtin_amdgcn_mfma_f32_32x32x16_bf16(ka1, q[kc], s1, 0, 0, 0);
    }

    // ---- online softmax; lane owns col n = l31 (tree reductions) ----
    float mx[16];
#pragma unroll
    for (int r = 0; r < 16; ++r) mx[r] = fmaxf(s0[r], s1[r]);
#pragma unroll
    for (int st = 8; st >= 1; st >>= 1)
#pragma unroll
      for (int r = 0; r < st; ++r) mx[r] = fmaxf(mx[r], mx[r + st]);
    const float tm = fmaxf(mx[0], __shfl_xor(mx[0], 32));

    if (__any(tm > m_run + 8.f)) {  // T13 defer-max
      const float mnew = fmaxf(m_run, tm);
      const float alpha = exp2f((m_run - mnew) * L2E);
      m_run = mnew;
      l_run *= alpha;
#pragma unroll
      for (int cf = 0; cf < 8; ++cf)
#pragma unroll
        for (int r = 0; r < 16; ++r) o[cf][r] *= alpha;
    }

    float sm[16];
#pragma unroll
    for (int r = 0; r < 16; ++r) {
      s0[r] = exp2f((s0[r] - m_run) * L2E);
      s1[r] = exp2f((s1[r] - m_run) * L2E);
      sm[r] = s0[r] + s1[r];
    }
#pragma unroll
    for (int st = 8; st >= 1; st >>= 1)
#pragma unroll
      for (int r = 0; r < st; ++r) sm[r] += sm[r + st];
    l_run += sm[0] + __shfl_xor(sm[0], 32);

    // ---- pack P (trunc), exchange m-quads with lane^32, O += P*V ----
    const char* Vp = bufC + 32768;
    const int cbase = l31 * 16;
#pragma unroll
    for (int sv = 0; sv < 2; ++sv) {
      const f32x16& s = sv ? s1 : s0;
#pragma unroll
      for (int ks = 0; ks < 2; ++ks) {
        const int ok = 8 * ks + 4 * h;
        const int os = 8 * ks + 4 * (1 - h);
        const unsigned uA = pack2t(s[ok], s[ok + 1]);
        const unsigned uB = pack2t(s[ok + 2], s[ok + 3]);
        const unsigned vA = pack2t(s[os], s[os + 1]);
        const unsigned vB = pack2t(s[os + 2], s[os + 3]);
        const unsigned xA = (unsigned)__shfl_xor((int)vA, 32);
        const unsigned xB = (unsigned)__shfl_xor((int)vB, 32);
        u32x4 fu;
        if (h == 0) { fu[0] = uA; fu[1] = uB; fu[2] = xA; fu[3] = xB; }
        else        { fu[0] = xA; fu[1] = xB; fu[2] = uA; fu[3] = uB; }
        const short8 pa = __builtin_bit_cast(short8, fu);
        // V chunk for this frag's k-slice: m in [sv*32+ks*16+8h, +8)
        const char* vbase = Vp + (sv * 4 + 2 * ks + h) * 4096 + cbase;
#pragma unroll
        for (int cf = 0; cf < 8; ++cf) {
          const short8 vb = *(const short8*)(vbase + cf * 512);
          o[cf] =
              __builtin_amdgcn_mfma_f32_32x32x16_bf16(pa, vb, o[cf], 0, 0, 0);
        }
      }
    }
    __syncthreads();  // reads done; next tile's DMA drained
  }

  // ---- epilogue: normalize, transpose via LDS (overlay), coalesced ----
  const float linv = 1.0f / l_run;
  float lr[16];
#pragma unroll
  for (int r = 0; r < 16; ++r)
    lr[r] = __shfl(linv, (r & 3) + 8 * (r >> 2) + 4 * h);
  const float gam = gamma[0];
  float* ot = (float*)smem + w * (32 * 129);
#pragma unroll
  for (int pass = 0; pass < 2; ++pass) {
#pragma unroll
    for (int cf = 0; cf < 4; ++cf) {
      const int cfg = pass * 4 + cf;
#pragma unroll
      for (int r = 0; r < 16; ++r) {
        const int nr = (r & 3) + 8 * (r >> 2) + 4 * h;
        ot[nr * 129 + cf * 32 + l31] = o[cfg][r] * lr[r];
      }
    }
    __syncthreads();
#pragma unroll 8
    for (int i = 0; i < 64; ++i) {
      const int cl = 2 * i + h;
      const float ov = ot[l31 * 129 + cl];
      const size_t gi =
          ((size_t)(b * NC + pass * 128 + cl)) * NNN + n0w + l31;
      out[gi] = gam * ov + x[gi];
    }
    __syncthreads();
  }
}

extern "C" void kernel_launch(void* const* d_in, const int* in_sizes, int n_in,
                              void* d_out, int out_size, void* d_ws,
                              size_t ws_size, hipStream_t stream) {
  const float* x = (const float*)d_in[0];
  const float* gamma = (const float*)d_in[1];
  float* out = (float*)d_out;
  ushort* fTs = (ushort*)d_ws;                // 16.78 MB
  ushort* fVs = fTs + (size_t)NB * NNN * NC;  // 16.78 MB

  dim3 pg(NNN / 32, NC / 32, NB);
  dim3 pb(32, 8, 1);
  prep_T<<<pg, pb, 0, stream>>>(x, fTs);
  prep_V<<<dim3(64, 8, NB), dim3(256), 0, stream>>>(x, fVs);

  attn_kernel<<<dim3(256), dim3(256), 0, stream>>>(x, fTs, fVs, gamma, out);
}

// Round 11
// 246.412 us; speedup vs baseline: 1.4289x; 1.4289x over previous
//
#include <hip/hip_runtime.h>
#include <hip/hip_bf16.h>

typedef __attribute__((ext_vector_type(8))) short short8;
typedef __attribute__((ext_vector_type(4))) float f32x4;
typedef __attribute__((ext_vector_type(16))) float f32x16;
typedef __attribute__((ext_vector_type(4))) unsigned int u32x4;

#define NB 8
#define NC 256
#define NNN 4096
#define L2E 1.44269504088896f

__device__ __forceinline__ ushort f2bf(float f) {
  __hip_bfloat16 h = __float2bfloat16(f);
  return *reinterpret_cast<ushort*>(&h);
}
__device__ __forceinline__ unsigned pack2(float a, float b) {
  return (unsigned)f2bf(a) | ((unsigned)f2bf(b) << 16);
}
__device__ __forceinline__ void gload16(const void* g, void* l) {
  __builtin_amdgcn_global_load_lds(
      (const __attribute__((address_space(1))) void*)g,
      (__attribute__((address_space(3))) void*)l, 16, 0, 0);
}

// fTs[b][n][c ^ ((n&7)<<3)] = bf16(x[b][c][n])   (chunk-swizzled rows, 512B)
__global__ __launch_bounds__(256) void prep_T(const float* __restrict__ x,
                                              ushort* __restrict__ fTs) {
  __shared__ float tile[32][33];
  const int tx = threadIdx.x, ty = threadIdx.y;
  const int n0 = blockIdx.x * 32, c0 = blockIdx.y * 32, b = blockIdx.z;
#pragma unroll
  for (int k = 0; k < 4; ++k) {
    tile[ty + 8 * k][tx] =
        x[((size_t)(b * NC + c0 + ty + 8 * k)) * NNN + n0 + tx];
  }
  __syncthreads();
#pragma unroll
  for (int k = 0; k < 4; ++k) {
    const int n = n0 + ty + 8 * k;
    const int c = c0 + tx;
    fTs[(size_t)(b * NNN + n) * NC + (c ^ ((n & 7) << 3))] =
        f2bf(tile[tx][ty + 8 * k]);
  }
}

// fVs[b][c][64t + (mm ^ ((c&7)<<3))] = bf16(x[b][c][64t+mm])
__global__ __launch_bounds__(256) void prep_V(const float* __restrict__ x,
                                              ushort* __restrict__ fVs) {
  const size_t ci = (size_t)blockIdx.x * 256 + threadIdx.x;  // 1M chunks
  const int p = (int)(ci & 511);
  const int c = (int)((ci >> 9) & 255);
  const int b = (int)(ci >> 17);
  const int lp = (p & ~7) | ((p & 7) ^ (c & 7));  // logical chunk
  const float* src = x + ((size_t)(b * NC + c)) * NNN + lp * 8;
  f32x4 a0 = *(const f32x4*)src;
  f32x4 a1 = *(const f32x4*)(src + 4);
  short8 w;
  w[0] = (short)f2bf(a0[0]); w[1] = (short)f2bf(a0[1]);
  w[2] = (short)f2bf(a0[2]); w[3] = (short)f2bf(a0[3]);
  w[4] = (short)f2bf(a1[0]); w[5] = (short)f2bf(a1[1]);
  w[6] = (short)f2bf(a1[2]); w[7] = (short)f2bf(a1[3]);
  *(short8*)(fVs + ((size_t)(b * NC + c)) * NNN + p * 8) = w;
}

// Flash attention, 32x32x16 bf16 MFMA, swapped QK^T, in-register softmax.
// R4 base, software-pipelined: cluster[ QK(t+1) || PV(t) ] between barriers.
__global__ __launch_bounds__(256, 1) void attn_kernel(
    const float* __restrict__ x, const ushort* __restrict__ fTs,
    const ushort* __restrict__ fVs, const float* __restrict__ gamma,
    float* __restrict__ out) {
  __shared__ __align__(16) char smem[131072];

  const int tid = threadIdx.x;
  const int w = tid >> 6;
  const int l = tid & 63;
  const int l31 = l & 31;
  const int h = l >> 5;
  const int b = blockIdx.x & 7;             // batch -> XCD
  const int gn0 = (blockIdx.x >> 3) << 7;   // query-row base of block
  const int n0w = gn0 + w * 32;             // this wave's 32 query cols

  const char* fTb = (const char*)(fTs + (size_t)b * NNN * NC);
  const char* fVb = (const char*)(fVs + (size_t)b * NNN * NC);

  // Q fragments (B operand): col n = l31 -> row n0w+l31; k = kc*16+8h+j
  short8 q[16];
  {
    const int n = n0w + l31;
    const char* qrow = fTb + (size_t)n * 512;
    const int sw = (n & 7) << 4;
#pragma unroll
    for (int kc = 0; kc < 16; ++kc)
      q[kc] = *(const short8*)(qrow + ((kc * 32 + 16 * h) ^ sw));
  }

  f32x16 o[8];
#pragma unroll
  for (int cf = 0; cf < 8; ++cf)
#pragma unroll
    for (int r = 0; r < 16; ++r) o[cf][r] = 0.f;
  float m_run = -3.0e38f, l_run = 0.f;

  // staging source addresses (per-lane), dest linear per wave (R4 verbatim)
  const int krow = w * 16 + (l >> 5);
  const char* gK0 = fTb + (size_t)krow * 512 + (l & 31) * 16;
  const char* gV0 = fVb + (size_t)(w * 64 + (l >> 3)) * 8192 + (l & 7) * 16;

#define STAGE_K(tt, base)                                                   \
  {                                                                         \
    const size_t kOff = (size_t)(tt) * 32768;                               \
    _Pragma("unroll") for (int i = 0; i < 8; ++i)                           \
        gload16(gK0 + kOff + (size_t)i * 1024, (base) + w * 8192 + i * 1024); \
  }
#define STAGE_V(tt, base)                                                   \
  {                                                                         \
    const size_t vOff = (size_t)(tt) * 128;                                 \
    _Pragma("unroll") for (int i = 0; i < 8; ++i)                           \
        gload16(gV0 + vOff + (size_t)i * 65536,                             \
                (base) + 32768 + w * 8192 + i * 1024);                      \
  }

// QK block: 32 MFMAs (two independent 16-chains) from K-region of KBASE
#define QKBLK(KBASE, S0, S1)                                                \
  {                                                                         \
    _Pragma("unroll") for (int r = 0; r < 16; ++r) {                        \
      (S0)[r] = 0.f; (S1)[r] = 0.f;                                         \
    }                                                                       \
    _Pragma("unroll") for (int kc = 0; kc < 16; ++kc) {                     \
      const int bb = (kc * 32 + 16 * h) ^ ((l31 & 7) << 4);                 \
      short8 ka0 = *(const short8*)((KBASE) + l31 * 512 + bb);              \
      short8 ka1 = *(const short8*)((KBASE) + (32 + l31) * 512 + bb);       \
      (S0) = __builtin_amdgcn_mfma_f32_32x32x16_bf16(ka0, q[kc], (S0), 0, 0, 0); \
      (S1) = __builtin_amdgcn_mfma_f32_32x32x16_bf16(ka1, q[kc], (S1), 0, 0, 0); \
    }                                                                       \
  }

  // prologue: tile 0 -> buf0; then issue tile 1 -> buf1; QK(0)
  STAGE_K(0, smem);
  STAGE_V(0, smem);
  __syncthreads();
  STAGE_K(1, smem + 65536);
  STAGE_V(1, smem + 65536);

  f32x16 s0, s1, n0v, n1v;
  QKBLK(smem, s0, s1);

  for (int t = 0; t < 64; ++t) {
    char* bufP = smem + (t & 1) * 65536;        // tile t (V pending, K done)
    char* bufN = smem + ((t + 1) & 1) * 65536;  // tile t+1 (K for QK(t+1))

    // ---- online softmax on s0,s1; lane owns col n = l31 (R4 verbatim) ----
    float tm = s0[0];
#pragma unroll
    for (int r = 1; r < 16; ++r) tm = fmaxf(tm, s0[r]);
#pragma unroll
    for (int r = 0; r < 16; ++r) tm = fmaxf(tm, s1[r]);
    tm = fmaxf(tm, __shfl_xor(tm, 32));

    if (__any(tm > m_run + 8.f)) {  // T13 defer-max
      const float mnew = fmaxf(m_run, tm);
      const float alpha = exp2f((m_run - mnew) * L2E);
      m_run = mnew;
      l_run *= alpha;
#pragma unroll
      for (int cf = 0; cf < 8; ++cf)
#pragma unroll
        for (int r = 0; r < 16; ++r) o[cf][r] *= alpha;
    }

    float rsum = 0.f;
#pragma unroll
    for (int r = 0; r < 16; ++r) {
      const float pv = exp2f((s0[r] - m_run) * L2E); s0[r] = pv; rsum += pv;
    }
#pragma unroll
    for (int r = 0; r < 16; ++r) {
      const float pv = exp2f((s1[r] - m_run) * L2E); s1[r] = pv; rsum += pv;
    }
    rsum += __shfl_xor(rsum, 32);
    l_run += rsum;

    // ---- pack P to bf16 dwords + exchange with lane^32 (R4 verbatim) ----
    unsigned d0[8], d1[8];
#pragma unroll
    for (int k = 0; k < 8; ++k) {
      const int rg = 4 * (k >> 1) + 2 * (k & 1);
      d0[k] = pack2(s0[rg], s0[rg + 1]);
      d1[k] = pack2(s1[rg], s1[rg + 1]);
    }
    unsigned x0[4], x1[4];
#pragma unroll
    for (int j = 0; j < 4; ++j) {
      const int iH1 = (j < 2) ? j : j + 2;      // what h==1 sends
      const int iH0 = (j < 2) ? j + 2 : j + 4;  // what h==0 sends
      unsigned s0v = h ? d0[iH1] : d0[iH0];
      unsigned s1v = h ? d1[iH1] : d1[iH0];
      x0[j] = (unsigned)__shfl_xor((int)s0v, 32);
      x1[j] = (unsigned)__shfl_xor((int)s1v, 32);
    }

    __syncthreads();  // drains stage(t+1); all waves past QK(t) reads

    if (t < 62) STAGE_K(t + 2, bufP);  // K(t) region free; window = cluster+

    // ======== cluster: QK(t+1) [bufN] || PV(t) [bufP V-region] ========
    if (t < 63) QKBLK(bufN, n0v, n1v);

    const char* Vp = bufP + 32768;
#pragma unroll
    for (int ks = 0; ks < 4; ++ks) {
      const int e = ks & 1;
      unsigned fa0, fa1, fa2, fa3;
      if (ks < 2) {
        fa0 = h ? x0[2 * e] : d0[4 * e];
        fa1 = h ? x0[2 * e + 1] : d0[4 * e + 1];
        fa2 = h ? d0[4 * e + 2] : x0[2 * e];
        fa3 = h ? d0[4 * e + 3] : x0[2 * e + 1];
      } else {
        fa0 = h ? x1[2 * e] : d1[4 * e];
        fa1 = h ? x1[2 * e + 1] : d1[4 * e + 1];
        fa2 = h ? d1[4 * e + 2] : x1[2 * e];
        fa3 = h ? d1[4 * e + 3] : x1[2 * e + 1];
      }
      u32x4 fu = {fa0, fa1, fa2, fa3};
      short8 pa = __builtin_bit_cast(short8, fu);
#pragma unroll
      for (int cf = 0; cf < 8; ++cf) {
        const int c = cf * 32 + l31;
        const int byte = (ks * 32 + 16 * h) ^ ((c & 7) << 4);
        short8 vb = *(const short8*)(Vp + c * 128 + byte);
        o[cf] = __builtin_amdgcn_mfma_f32_32x32x16_bf16(pa, vb, o[cf], 0, 0, 0);
      }
    }
    // ===================================================================

    __syncthreads();  // all reads of bufP done

    if (t < 62) STAGE_V(t + 2, bufP);  // V(t) region free

    if (t < 63) { s0 = n0v; s1 = n1v; }
  }
#undef STAGE_K
#undef STAGE_V
#undef QKBLK

  // ---- epilogue: normalize, transpose via LDS (overlay), coalesced ----
  const float linv = 1.0f / l_run;
  float lr[16];
#pragma unroll
  for (int r = 0; r < 16; ++r)
    lr[r] = __shfl(linv, (r & 3) + 8 * (r >> 2) + 4 * h);
  const float gam = gamma[0];
  float* ot = (float*)smem + w * (32 * 129);
#pragma unroll
  for (int pass = 0; pass < 2; ++pass) {
#pragma unroll
    for (int cf = 0; cf < 4; ++cf) {
      const int cfg = pass * 4 + cf;
#pragma unroll
      for (int r = 0; r < 16; ++r) {
        const int nr = (r & 3) + 8 * (r >> 2) + 4 * h;
        ot[nr * 129 + cf * 32 + l31] = o[cfg][r] * lr[r];
      }
    }
    __syncthreads();
#pragma unroll 8
    for (int i = 0; i < 64; ++i) {
      const int cl = 2 * i + h;
      const float ov = ot[l31 * 129 + cl];
      const size_t gi =
          ((size_t)(b * NC + pass * 128 + cl)) * NNN + n0w + l31;
      out[gi] = gam * ov + x[gi];
    }
    __syncthreads();
  }
}

extern "C" void kernel_launch(void* const* d_in, const int* in_sizes, int n_in,
                              void* d_out, int out_size, void* d_ws,
                              size_t ws_size, hipStream_t stream) {
  const float* x = (const float*)d_in[0];
  const float* gamma = (const float*)d_in[1];
  float* out = (float*)d_out;
  ushort* fTs = (ushort*)d_ws;                // 16.78 MB
  ushort* fVs = fTs + (size_t)NB * NNN * NC;  // 16.78 MB

  dim3 pg(NNN / 32, NC / 32, NB);
  dim3 pb(32, 8, 1);
  prep_T<<<pg, pb, 0, stream>>>(x, fTs);
  prep_V<<<dim3(4096), dim3(256), 0, stream>>>(x, fVs);

  attn_kernel<<<dim3(256), dim3(256), 0, stream>>>(x, fTs, fVs, gamma, out);
}